// Round 1
// baseline (1006.570 us; speedup 1.0000x reference)
//
#include <hip/hip_runtime.h>
#include <hip/hip_bf16.h>
#include <math.h>

typedef __bf16 bf16_t;
typedef bf16_t bf16x8 __attribute__((ext_vector_type(8)));
typedef bf16_t bf16x4 __attribute__((ext_vector_type(4)));
typedef float  f32x4  __attribute__((ext_vector_type(4)));

#define HIDDEN 4096
#define NH     32
#define NKV    8
#define HD     128
#define QSZ    4096
#define KVSZ   1024
#define QKVN   6144
#define SEQ    2048
#define ATT_SCALE 0.08838834764831845f   // 1/sqrt(128)
#define KEYMUL 0.5f

// ---- async global->LDS (16B per lane) ----
static __device__ __forceinline__ void gld_lds16(const void* g, void* l) {
  __builtin_amdgcn_global_load_lds((const __attribute__((address_space(1))) char*)g,
                                   (__attribute__((address_space(3))) char*)l, 16, 0, 0);
}

// ---- elementwise fp32 -> bf16 cast ----
__global__ __launch_bounds__(256) void cast_f32_bf16(const float* __restrict__ in,
                                                     bf16_t* __restrict__ out) {
  int i = (blockIdx.x * 256 + threadIdx.x) * 4;
  float4 v = *(const float4*)(in + i);
  bf16x4 o;
  o[0] = (bf16_t)v.x; o[1] = (bf16_t)v.y; o[2] = (bf16_t)v.z; o[3] = (bf16_t)v.w;
  *(bf16x4*)(out + i) = o;
}

// ---- transpose + cast: W[K][N] f32 -> WT[N][K] bf16 ----
__global__ __launch_bounds__(256) void transpose_cast(const float* __restrict__ W,
                                                      bf16_t* __restrict__ WT,
                                                      int K, int N) {
  __shared__ float t[32][33];
  int k0 = blockIdx.y * 32, n0 = blockIdx.x * 32;
  int c = threadIdx.x & 31, r = threadIdx.x >> 5;
#pragma unroll
  for (int rr = r; rr < 32; rr += 8)
    t[rr][c] = W[(size_t)(k0 + rr) * N + n0 + c];
  __syncthreads();
#pragma unroll
  for (int rr = r; rr < 32; rr += 8)
    WT[(size_t)(n0 + rr) * K + k0 + c] = (bf16_t)t[c][rr];
}

// ---- V slice of qkv -> VT[kvh][d][s] bf16 (transposed for PV B-operand) ----
__global__ __launch_bounds__(256) void vprep(const float* __restrict__ qkv,
                                             bf16_t* __restrict__ VT) {
  __shared__ float t[32][33];
  int h = blockIdx.z;
  int s0 = blockIdx.x * 32, d0 = blockIdx.y * 32;
  int c = threadIdx.x & 31, r = threadIdx.x >> 5;
#pragma unroll
  for (int rr = r; rr < 32; rr += 8)
    t[rr][c] = qkv[(size_t)(s0 + rr) * QKVN + QSZ + KVSZ + h * HD + d0 + c];
  __syncthreads();
#pragma unroll
  for (int rr = r; rr < 32; rr += 8)
    VT[((size_t)h * HD + d0 + rr) * SEQ + s0 + c] = (bf16_t)t[c][rr];
}

// ---- RoPE (neox) on q and k, fp32 math, writes head-major bf16 ----
__global__ __launch_bounds__(256) void rope_qk(const float* __restrict__ qkv,
                                               const int* __restrict__ positions,
                                               bf16_t* __restrict__ Qh,
                                               bf16_t* __restrict__ Kh) {
  int s = blockIdx.x;
  float pos = (float)positions[s];
  for (int p = threadIdx.x; p < (NH + NKV) * 64; p += 256) {
    int i = p & 63;
    float inv = powf(100000000000.0f, -(float)i * (1.0f / 64.0f));
    float fr = pos * inv;
    float cs = cosf(fr), sn = sinf(fr);
    if (p < NH * 64) {
      int hh = p >> 6;
      const float* base = qkv + (size_t)s * QKVN + hh * HD;
      float x1 = base[i], x2 = base[i + 64];
      bf16_t* ob = Qh + ((size_t)hh * SEQ + s) * HD;
      ob[i]      = (bf16_t)(x1 * cs - x2 * sn);
      ob[i + 64] = (bf16_t)(x2 * cs + x1 * sn);
    } else {
      int hh = (p - NH * 64) >> 6;
      const float* base = qkv + (size_t)s * QKVN + QSZ + hh * HD;
      float x1 = base[i], x2 = base[i + 64];
      bf16_t* ob = Kh + ((size_t)hh * SEQ + s) * HD;
      ob[i]      = (bf16_t)((x1 * cs - x2 * sn) * KEYMUL);
      ob[i + 64] = (bf16_t)((x2 * cs + x1 * sn) * KEYMUL);
    }
  }
}

// ---- bf16 GEMM, m97 structure: C[M][N] f32 = A[M][K] * BT[N][K]^T ----
// 128x128 tile, BK=32, 256 threads (4 waves 2x2, each 64x64)
__global__ __launch_bounds__(256) void gemm_bf16_bt(const bf16_t* __restrict__ A,
                                                    const bf16_t* __restrict__ BT,
                                                    float* __restrict__ C,
                                                    int M, int N, int K) {
  __shared__ __align__(16) bf16_t lA[128 * 32];
  __shared__ __align__(16) bf16_t lB[128 * 32];
  int tid = threadIdx.x;
  int w = tid >> 6, lane = tid & 63;
  int l16 = lane & 15, lhi = lane >> 4;
  int bm = blockIdx.y, bn = blockIdx.x;
  int wm = (w >> 1) * 64, wn = (w & 1) * 64;
  int rowA0 = bm * 128, rowB0 = bn * 128;
  f32x4 acc[4][4] = {};
  int c0 = w * 128 + lane;
  int c1 = c0 + 64;
  const bf16_t* Asrc0 = A + (size_t)(rowA0 + (c0 >> 2)) * K + (c0 & 3) * 8;
  const bf16_t* Asrc1 = A + (size_t)(rowA0 + (c1 >> 2)) * K + (c1 & 3) * 8;
  const bf16_t* Bsrc0 = BT + (size_t)(rowB0 + (c0 >> 2)) * K + (c0 & 3) * 8;
  const bf16_t* Bsrc1 = BT + (size_t)(rowB0 + (c1 >> 2)) * K + (c1 & 3) * 8;

  for (int kt = 0; kt < K; kt += 32) {
    gld_lds16(Asrc0 + kt, lA + c0 * 8);
    gld_lds16(Asrc1 + kt, lA + c1 * 8);
    gld_lds16(Bsrc0 + kt, lB + c0 * 8);
    gld_lds16(Bsrc1 + kt, lB + c1 * 8);
    __syncthreads();
    bf16x8 af[4], bfr[4];
#pragma unroll
    for (int m = 0; m < 4; ++m)
      af[m] = *(const bf16x8*)(lA + (wm + m * 16 + l16) * 32 + lhi * 8);
#pragma unroll
    for (int n = 0; n < 4; ++n)
      bfr[n] = *(const bf16x8*)(lB + (wn + n * 16 + l16) * 32 + lhi * 8);
#pragma unroll
    for (int m = 0; m < 4; ++m)
#pragma unroll
      for (int n = 0; n < 4; ++n)
        acc[m][n] = __builtin_amdgcn_mfma_f32_16x16x32_bf16(af[m], bfr[n], acc[m][n], 0, 0, 0);
    __syncthreads();
  }
#pragma unroll
  for (int m = 0; m < 4; ++m) {
    int row = rowA0 + wm + m * 16 + lhi * 4;
#pragma unroll
    for (int n = 0; n < 4; ++n) {
      int col = rowB0 + wn + n * 16 + l16;
#pragma unroll
      for (int j = 0; j < 4; ++j)
        C[(size_t)(row + j) * N + col] = acc[m][n][j];
    }
  }
}

// ---- flash-style causal GQA attention, bf16 MFMA + fp32 online softmax ----
// grid (SEQ/64, NH); 256 threads = 4 waves, each wave owns 16 q-rows.
__global__ __launch_bounds__(256) void attn_kernel(const bf16_t* __restrict__ Q,   // [NH][SEQ][HD]
                                                   const bf16_t* __restrict__ Kb,  // [NKV][SEQ][HD]
                                                   const bf16_t* __restrict__ VT,  // [NKV][HD][SEQ]
                                                   bf16_t* __restrict__ Oa) {      // [SEQ][QSZ]
  __shared__ __align__(16) bf16_t Plds[4][16][72];
  int h = blockIdx.y, qt = blockIdx.x;
  int kvh = h >> 2;
  int tid = threadIdx.x;
  int w = tid >> 6, lane = tid & 63;
  int l16 = lane & 15, lhi = lane >> 4;
  int qrow0 = qt * 64 + w * 16;

  bf16x8 qf[4];
  const bf16_t* qbase = Q + ((size_t)h * SEQ + qrow0 + l16) * HD;
#pragma unroll
  for (int kk = 0; kk < 4; ++kk)
    qf[kk] = *(const bf16x8*)(qbase + kk * 32 + lhi * 8);

  f32x4 o[8] = {};
  float m_r[4], l_r[4];
#pragma unroll
  for (int j = 0; j < 4; ++j) { m_r[j] = -1e30f; l_r[j] = 0.0f; }

  int ntile = qt + 1;
  for (int kt = 0; kt < ntile; ++kt) {
    int kb = kt * 64;
    // --- QK^T ---
    f32x4 s4[4] = {};
    const bf16_t* kbase = Kb + ((size_t)kvh * SEQ + kb) * HD;
#pragma unroll
    for (int n = 0; n < 4; ++n) {
      const bf16_t* kp = kbase + (size_t)(n * 16 + l16) * HD + lhi * 8;
#pragma unroll
      for (int kk = 0; kk < 4; ++kk)
        s4[n] = __builtin_amdgcn_mfma_f32_16x16x32_bf16(qf[kk], *(const bf16x8*)(kp + kk * 32), s4[n], 0, 0, 0);
    }
    // --- scale + causal mask ---
    float p[4][4];
#pragma unroll
    for (int n = 0; n < 4; ++n) {
      int col = kb + n * 16 + l16;
#pragma unroll
      for (int j = 0; j < 4; ++j) {
        int row = qrow0 + lhi * 4 + j;
        float v = s4[n][j] * ATT_SCALE;
        p[n][j] = (col > row) ? -1e30f : v;
      }
    }
    // --- row max (across 4 n-frags and 16 lanes of the group) ---
    float mx[4];
#pragma unroll
    for (int j = 0; j < 4; ++j) {
      mx[j] = fmaxf(fmaxf(p[0][j], p[1][j]), fmaxf(p[2][j], p[3][j]));
#pragma unroll
      for (int d = 1; d < 16; d <<= 1)
        mx[j] = fmaxf(mx[j], __shfl_xor(mx[j], d));
    }
    float mn[4], sc[4], rs[4];
#pragma unroll
    for (int j = 0; j < 4; ++j) {
      mn[j] = fmaxf(m_r[j], mx[j]);
      sc[j] = __expf(m_r[j] - mn[j]);
      m_r[j] = mn[j];
    }
#pragma unroll
    for (int n = 0; n < 4; ++n)
#pragma unroll
      for (int j = 0; j < 4; ++j)
        p[n][j] = __expf(p[n][j] - mn[j]);
#pragma unroll
    for (int j = 0; j < 4; ++j) {
      rs[j] = p[0][j] + p[1][j] + p[2][j] + p[3][j];
#pragma unroll
      for (int d = 1; d < 16; d <<= 1)
        rs[j] += __shfl_xor(rs[j], d);
      l_r[j] = l_r[j] * sc[j] + rs[j];
    }
#pragma unroll
    for (int nf = 0; nf < 8; ++nf)
#pragma unroll
      for (int j = 0; j < 4; ++j)
        o[nf][j] *= sc[j];
    // --- P -> LDS (bf16, A-frag layout) ---
#pragma unroll
    for (int n = 0; n < 4; ++n)
#pragma unroll
      for (int j = 0; j < 4; ++j)
        Plds[w][lhi * 4 + j][n * 16 + l16] = (bf16_t)p[n][j];
    __syncthreads();
    // --- PV ---
#pragma unroll
    for (int ks = 0; ks < 2; ++ks) {
      bf16x8 pa = *(const bf16x8*)&Plds[w][l16][ks * 32 + lhi * 8];
      const bf16_t* vbase = VT + ((size_t)kvh * HD + l16) * SEQ + kb + ks * 32 + lhi * 8;
#pragma unroll
      for (int nf = 0; nf < 8; ++nf)
        o[nf] = __builtin_amdgcn_mfma_f32_16x16x32_bf16(pa, *(const bf16x8*)(vbase + (size_t)nf * 16 * SEQ), o[nf], 0, 0, 0);
    }
    __syncthreads();
  }
  // --- epilogue: normalize, write bf16 [SEQ][QSZ] ---
#pragma unroll
  for (int j = 0; j < 4; ++j) {
    float inv_l = 1.0f / l_r[j];
    int row = qrow0 + lhi * 4 + j;
#pragma unroll
    for (int nf = 0; nf < 8; ++nf)
      Oa[(size_t)row * QSZ + h * HD + nf * 16 + l16] = (bf16_t)(o[nf][j] * inv_l);
  }
}

extern "C" void kernel_launch(void* const* d_in, const int* in_sizes, int n_in,
                              void* d_out, int out_size, void* d_ws, size_t ws_size,
                              hipStream_t stream) {
  const int*   positions = (const int*)d_in[0];
  const float* hidden    = (const float*)d_in[1];
  const float* w_qkv     = (const float*)d_in[2];
  const float* w_o       = (const float*)d_in[3];
  float* out = (float*)d_out;

  char* ws = (char*)d_ws;
  size_t off = 0;
  auto alloc = [&](size_t bytes) { void* p = ws + off; off += (bytes + 255) & ~255ULL; return p; };
  bf16_t* h_bf  = (bf16_t*)alloc((size_t)SEQ * HIDDEN * 2);
  bf16_t* wqkvT = (bf16_t*)alloc((size_t)QKVN * HIDDEN * 2);
  bf16_t* woT   = (bf16_t*)alloc((size_t)HIDDEN * QSZ * 2);
  float*  qkv   = (float*)alloc((size_t)SEQ * QKVN * 4);
  bf16_t* Qh    = (bf16_t*)alloc((size_t)NH * SEQ * HD * 2);
  bf16_t* Kh    = (bf16_t*)alloc((size_t)NKV * SEQ * HD * 2);
  bf16_t* VT    = (bf16_t*)alloc((size_t)NKV * HD * SEQ * 2);
  bf16_t* Oa    = (bf16_t*)alloc((size_t)SEQ * QSZ * 2);
  (void)ws_size; (void)in_sizes; (void)n_in; (void)out_size;

  cast_f32_bf16<<<SEQ * HIDDEN / 4 / 256, 256, 0, stream>>>(hidden, h_bf);
  transpose_cast<<<dim3(QKVN / 32, HIDDEN / 32), 256, 0, stream>>>(w_qkv, wqkvT, HIDDEN, QKVN);
  transpose_cast<<<dim3(HIDDEN / 32, QSZ / 32), 256, 0, stream>>>(w_o, woT, QSZ, HIDDEN);
  gemm_bf16_bt<<<dim3(QKVN / 128, SEQ / 128), 256, 0, stream>>>(h_bf, wqkvT, qkv, SEQ, QKVN, HIDDEN);
  rope_qk<<<SEQ, 256, 0, stream>>>(qkv, positions, Qh, Kh);
  vprep<<<dim3(SEQ / 32, HD / 32, NKV), 256, 0, stream>>>(qkv, VT);
  attn_kernel<<<dim3(SEQ / 64, NH), 256, 0, stream>>>(Qh, Kh, VT, Oa);
  gemm_bf16_bt<<<dim3(HIDDEN / 128, SEQ / 128), 256, 0, stream>>>(Oa, woT, out, SEQ, HIDDEN, QSZ);
}

// Round 4
// 601.459 us; speedup vs baseline: 1.6735x; 1.6735x over previous
//
#include <hip/hip_runtime.h>
#include <hip/hip_bf16.h>
#include <math.h>

typedef __bf16 bf16_t;
typedef bf16_t bf16x8 __attribute__((ext_vector_type(8)));
typedef bf16_t bf16x4 __attribute__((ext_vector_type(4)));
typedef float  f32x4  __attribute__((ext_vector_type(4)));

#define HIDDEN 4096
#define NH     32
#define NKV    8
#define HD     128
#define QSZ    4096
#define KVSZ   1024
#define QKVN   6144
#define SEQ    2048
#define ATT_SCALE 0.08838834764831845f   // 1/sqrt(128)
#define KEYMUL 0.5f

// ---- async global->LDS (16B per lane) ----
static __device__ __forceinline__ void gld_lds16(const void* g, void* l) {
  __builtin_amdgcn_global_load_lds((const __attribute__((address_space(1))) char*)g,
                                   (__attribute__((address_space(3))) char*)l, 16, 0, 0);
}

// ---- elementwise fp32 -> bf16 cast ----
__global__ __launch_bounds__(256) void cast_f32_bf16(const float* __restrict__ in,
                                                     bf16_t* __restrict__ out) {
  int i = (blockIdx.x * 256 + threadIdx.x) * 4;
  float4 v = *(const float4*)(in + i);
  bf16x4 o;
  o[0] = (bf16_t)v.x; o[1] = (bf16_t)v.y; o[2] = (bf16_t)v.z; o[3] = (bf16_t)v.w;
  *(bf16x4*)(out + i) = o;
}

// ---- transpose + cast: W[K][N] f32 -> WT[N][K] bf16 ----
__global__ __launch_bounds__(256) void transpose_cast(const float* __restrict__ W,
                                                      bf16_t* __restrict__ WT,
                                                      int K, int N) {
  __shared__ float t[32][33];
  int k0 = blockIdx.y * 32, n0 = blockIdx.x * 32;
  int c = threadIdx.x & 31, r = threadIdx.x >> 5;
#pragma unroll
  for (int rr = r; rr < 32; rr += 8)
    t[rr][c] = W[(size_t)(k0 + rr) * N + n0 + c];
  __syncthreads();
#pragma unroll
  for (int rr = r; rr < 32; rr += 8)
    WT[(size_t)(n0 + rr) * K + k0 + c] = (bf16_t)t[c][rr];
}

// ---- V slice of qkv -> VT[kvh][d][s] bf16 (transposed for PV B-operand) ----
__global__ __launch_bounds__(256) void vprep(const float* __restrict__ qkv,
                                             bf16_t* __restrict__ VT) {
  __shared__ float t[32][33];
  int h = blockIdx.z;
  int s0 = blockIdx.x * 32, d0 = blockIdx.y * 32;
  int c = threadIdx.x & 31, r = threadIdx.x >> 5;
#pragma unroll
  for (int rr = r; rr < 32; rr += 8)
    t[rr][c] = qkv[(size_t)(s0 + rr) * QKVN + QSZ + KVSZ + h * HD + d0 + c];
  __syncthreads();
#pragma unroll
  for (int rr = r; rr < 32; rr += 8)
    VT[((size_t)h * HD + d0 + rr) * SEQ + s0 + c] = (bf16_t)t[c][rr];
}

// ---- RoPE (neox) on q and k, fp32 math, writes head-major bf16 ----
__global__ __launch_bounds__(256) void rope_qk(const float* __restrict__ qkv,
                                               const int* __restrict__ positions,
                                               bf16_t* __restrict__ Qh,
                                               bf16_t* __restrict__ Kh) {
  int s = blockIdx.x;
  float pos = (float)positions[s];
  for (int p = threadIdx.x; p < (NH + NKV) * 64; p += 256) {
    int i = p & 63;
    float inv = powf(100000000000.0f, -(float)i * (1.0f / 64.0f));
    float fr = pos * inv;
    float cs = cosf(fr), sn = sinf(fr);
    if (p < NH * 64) {
      int hh = p >> 6;
      const float* base = qkv + (size_t)s * QKVN + hh * HD;
      float x1 = base[i], x2 = base[i + 64];
      bf16_t* ob = Qh + ((size_t)hh * SEQ + s) * HD;
      ob[i]      = (bf16_t)(x1 * cs - x2 * sn);
      ob[i + 64] = (bf16_t)(x2 * cs + x1 * sn);
    } else {
      int hh = (p - NH * 64) >> 6;
      const float* base = qkv + (size_t)s * QKVN + QSZ + hh * HD;
      float x1 = base[i], x2 = base[i + 64];
      bf16_t* ob = Kh + ((size_t)hh * SEQ + s) * HD;
      ob[i]      = (bf16_t)((x1 * cs - x2 * sn) * KEYMUL);
      ob[i + 64] = (bf16_t)((x2 * cs + x1 * sn) * KEYMUL);
    }
  }
}

// ---- bf16 GEMM, m97 structure: C[M][N] f32 = A[M][K] * BT[N][K]^T ----
__global__ __launch_bounds__(256) void gemm_bf16_bt(const bf16_t* __restrict__ A,
                                                    const bf16_t* __restrict__ BT,
                                                    float* __restrict__ C,
                                                    int M, int N, int K) {
  __shared__ __align__(16) bf16_t lA[128 * 32];
  __shared__ __align__(16) bf16_t lB[128 * 32];
  int tid = threadIdx.x;
  int w = tid >> 6, lane = tid & 63;
  int l16 = lane & 15, lhi = lane >> 4;
  int bm = blockIdx.y, bn = blockIdx.x;
  int wm = (w >> 1) * 64, wn = (w & 1) * 64;
  int rowA0 = bm * 128, rowB0 = bn * 128;
  f32x4 acc[4][4] = {};
  int c0 = w * 128 + lane;
  int c1 = c0 + 64;
  const bf16_t* Asrc0 = A + (size_t)(rowA0 + (c0 >> 2)) * K + (c0 & 3) * 8;
  const bf16_t* Asrc1 = A + (size_t)(rowA0 + (c1 >> 2)) * K + (c1 & 3) * 8;
  const bf16_t* Bsrc0 = BT + (size_t)(rowB0 + (c0 >> 2)) * K + (c0 & 3) * 8;
  const bf16_t* Bsrc1 = BT + (size_t)(rowB0 + (c1 >> 2)) * K + (c1 & 3) * 8;

  for (int kt = 0; kt < K; kt += 32) {
    gld_lds16(Asrc0 + kt, lA + c0 * 8);
    gld_lds16(Asrc1 + kt, lA + c1 * 8);
    gld_lds16(Bsrc0 + kt, lB + c0 * 8);
    gld_lds16(Bsrc1 + kt, lB + c1 * 8);
    __syncthreads();
    bf16x8 af[4], bfr[4];
#pragma unroll
    for (int m = 0; m < 4; ++m)
      af[m] = *(const bf16x8*)(lA + (wm + m * 16 + l16) * 32 + lhi * 8);
#pragma unroll
    for (int n = 0; n < 4; ++n)
      bfr[n] = *(const bf16x8*)(lB + (wn + n * 16 + l16) * 32 + lhi * 8);
#pragma unroll
    for (int m = 0; m < 4; ++m)
#pragma unroll
      for (int n = 0; n < 4; ++n)
        acc[m][n] = __builtin_amdgcn_mfma_f32_16x16x32_bf16(af[m], bfr[n], acc[m][n], 0, 0, 0);
    __syncthreads();
  }
#pragma unroll
  for (int m = 0; m < 4; ++m) {
    int row = rowA0 + wm + m * 16 + lhi * 4;
#pragma unroll
    for (int n = 0; n < 4; ++n) {
      int col = rowB0 + wn + n * 16 + l16;
#pragma unroll
      for (int j = 0; j < 4; ++j)
        C[(size_t)(row + j) * N + col] = acc[m][n][j];
    }
  }
}

// ---- flash-style causal GQA attention ----
// grid (16, NH): block p handles q-tiles {p, 31-p} -> 33 kv-tile iters per block
// (perfect balance; 512 blocks = exactly 2/CU at 74KB LDS).
// K/V tiles double-buffered in LDS via global_load_lds; XOR-swizzle (row&7)<<4
// applied on the pre-swizzled GLOBAL source + swizzled ds_read (rule #21).
__global__ __launch_bounds__(256) void attn_kernel(const bf16_t* __restrict__ Q,   // [NH][SEQ][HD]
                                                   const bf16_t* __restrict__ Kb,  // [NKV][SEQ][HD]
                                                   const bf16_t* __restrict__ VT,  // [NKV][HD][SEQ]
                                                   bf16_t* __restrict__ Oa) {      // [SEQ][QSZ]
  __shared__ __align__(16) char KV[2][2][16384];   // [buf][K=0/V=1][16KB]
  __shared__ __align__(16) bf16_t Plds[4][16][72];
  int h = blockIdx.y, p = blockIdx.x;
  int kvh = h >> 2;
  int tid = threadIdx.x;
  int w = tid >> 6, lane = tid & 63;
  int l16 = lane & 15, lhi = lane >> 4;
  int xr = (l16 & 7) << 4;

  // staging per-lane constants (issue i covers tile bytes [w*4096+i*1024, +1024))
  int kRow[4], kCol[4], vRow[4], vCol[4], ldsOff[4];
#pragma unroll
  for (int i = 0; i < 4; ++i) {
    int X = w * 4096 + i * 1024 + lane * 16;
    ldsOff[i] = X;
    kRow[i] = X >> 8;                                 // 0..63  (K rows, 256B each)
    kCol[i] = (X & 255) ^ ((kRow[i] & 7) << 4);
    vRow[i] = X >> 7;                                 // 0..127 (V rows, 128B each)
    vCol[i] = (X & 127) ^ ((vRow[i] & 7) << 4);
  }
  const char* Kg = (const char*)(Kb + (size_t)kvh * SEQ * HD);
  const char* Vg = (const char*)(VT + (size_t)kvh * HD * SEQ);

  int qts[2] = {p, 31 - p};
  int nts[2] = {p + 1, 32 - p};

  for (int ph = 0; ph < 2; ++ph) {
    int qt = qts[ph], ntile = nts[ph];
    int qrow0 = qt * 64 + w * 16;

    bf16x8 qf[4];
    const bf16_t* qbase = Q + ((size_t)h * SEQ + qrow0 + l16) * HD;
#pragma unroll
    for (int kk = 0; kk < 4; ++kk)
      qf[kk] = *(const bf16x8*)(qbase + kk * 32 + lhi * 8);

    f32x4 o[8] = {};
    float m_r[4], l_r[4];
#pragma unroll
    for (int j = 0; j < 4; ++j) { m_r[j] = -1e30f; l_r[j] = 0.0f; }

    // prologue: stage tile 0
#pragma unroll
    for (int i = 0; i < 4; ++i) {
      gld_lds16(Kg + (size_t)(0 + kRow[i]) * 256 + kCol[i], &KV[0][0][0] + ldsOff[i]);
      gld_lds16(Vg + (size_t)vRow[i] * (SEQ * 2) + 0 + vCol[i], &KV[0][1][0] + ldsOff[i]);
    }
    __syncthreads();

    for (int kt = 0; kt < ntile; ++kt) {
      int b = kt & 1;
      int kb = kt * 64;
      if (kt + 1 < ntile) {
        int kb2 = kb + 64;
#pragma unroll
        for (int i = 0; i < 4; ++i) {
          gld_lds16(Kg + (size_t)(kb2 + kRow[i]) * 256 + kCol[i], &KV[b ^ 1][0][0] + ldsOff[i]);
          gld_lds16(Vg + (size_t)vRow[i] * (SEQ * 2) + (size_t)kb2 * 2 + vCol[i], &KV[b ^ 1][1][0] + ldsOff[i]);
        }
      }
      const char* Kl = &KV[b][0][0];
      const char* Vl = &KV[b][1][0];

      // --- QK^T from LDS (swizzled reads) ---
      f32x4 s4[4] = {};
#pragma unroll
      for (int n = 0; n < 4; ++n) {
        int r = n * 16 + l16;
#pragma unroll
        for (int kk = 0; kk < 4; ++kk) {
          bf16x8 kf = *(const bf16x8*)(Kl + r * 256 + ((kk * 64 + lhi * 16) ^ xr));
          s4[n] = __builtin_amdgcn_mfma_f32_16x16x32_bf16(qf[kk], kf, s4[n], 0, 0, 0);
        }
      }
      // --- scale + causal mask ---
      float pv[4][4];
#pragma unroll
      for (int n = 0; n < 4; ++n) {
        int col = kb + n * 16 + l16;
#pragma unroll
        for (int j = 0; j < 4; ++j) {
          int row = qrow0 + lhi * 4 + j;
          float v = s4[n][j] * ATT_SCALE;
          pv[n][j] = (col > row) ? -1e30f : v;
        }
      }
      // --- online softmax ---
      float mx[4];
#pragma unroll
      for (int j = 0; j < 4; ++j) {
        mx[j] = fmaxf(fmaxf(pv[0][j], pv[1][j]), fmaxf(pv[2][j], pv[3][j]));
#pragma unroll
        for (int d = 1; d < 16; d <<= 1)
          mx[j] = fmaxf(mx[j], __shfl_xor(mx[j], d));
      }
      float mn[4], sc[4], rs[4];
#pragma unroll
      for (int j = 0; j < 4; ++j) {
        mn[j] = fmaxf(m_r[j], mx[j]);
        sc[j] = __expf(m_r[j] - mn[j]);
        m_r[j] = mn[j];
      }
#pragma unroll
      for (int n = 0; n < 4; ++n)
#pragma unroll
        for (int j = 0; j < 4; ++j)
          pv[n][j] = __expf(pv[n][j] - mn[j]);
#pragma unroll
      for (int j = 0; j < 4; ++j) {
        rs[j] = pv[0][j] + pv[1][j] + pv[2][j] + pv[3][j];
#pragma unroll
        for (int d = 1; d < 16; d <<= 1)
          rs[j] += __shfl_xor(rs[j], d);
        l_r[j] = l_r[j] * sc[j] + rs[j];
      }
#pragma unroll
      for (int nf = 0; nf < 8; ++nf)
#pragma unroll
        for (int j = 0; j < 4; ++j)
          o[nf][j] *= sc[j];
      // --- P -> LDS (per-wave private slice; compiler inserts lgkmcnt) ---
#pragma unroll
      for (int n = 0; n < 4; ++n)
#pragma unroll
        for (int j = 0; j < 4; ++j)
          Plds[w][lhi * 4 + j][n * 16 + l16] = (bf16_t)pv[n][j];
      // --- PV from LDS (swizzled reads) ---
#pragma unroll
      for (int ks = 0; ks < 2; ++ks) {
        bf16x8 pa = *(const bf16x8*)&Plds[w][l16][ks * 32 + lhi * 8];
#pragma unroll
        for (int nf = 0; nf < 8; ++nf) {
          int d = nf * 16 + l16;
          bf16x8 vf = *(const bf16x8*)(Vl + d * 128 + ((ks * 64 + lhi * 16) ^ xr));
          o[nf] = __builtin_amdgcn_mfma_f32_16x16x32_bf16(pa, vf, o[nf], 0, 0, 0);
        }
      }
      __syncthreads();   // drains vmcnt(0): next tile's K/V landed; buffers safe to swap
    }
    // --- epilogue ---
#pragma unroll
    for (int j = 0; j < 4; ++j) {
      float inv_l = 1.0f / l_r[j];
      int row = qrow0 + lhi * 4 + j;
#pragma unroll
      for (int nf = 0; nf < 8; ++nf)
        Oa[(size_t)row * QSZ + h * HD + nf * 16 + l16] = (bf16_t)(o[nf][j] * inv_l);
    }
    __syncthreads();   // phase boundary: all waves done before re-staging buf0
  }
}

extern "C" void kernel_launch(void* const* d_in, const int* in_sizes, int n_in,
                              void* d_out, int out_size, void* d_ws, size_t ws_size,
                              hipStream_t stream) {
  const int*   positions = (const int*)d_in[0];
  const float* hidden    = (const float*)d_in[1];
  const float* w_qkv     = (const float*)d_in[2];
  const float* w_o       = (const float*)d_in[3];
  float* out = (float*)d_out;

  char* ws = (char*)d_ws;
  size_t off = 0;
  auto alloc = [&](size_t bytes) { void* p = ws + off; off += (bytes + 255) & ~255ULL; return p; };
  bf16_t* h_bf  = (bf16_t*)alloc((size_t)SEQ * HIDDEN * 2);
  bf16_t* wqkvT = (bf16_t*)alloc((size_t)QKVN * HIDDEN * 2);
  bf16_t* woT   = (bf16_t*)alloc((size_t)HIDDEN * QSZ * 2);
  float*  qkv   = (float*)alloc((size_t)SEQ * QKVN * 4);
  bf16_t* Qh    = (bf16_t*)alloc((size_t)NH * SEQ * HD * 2);
  bf16_t* Kh    = (bf16_t*)alloc((size_t)NKV * SEQ * HD * 2);
  bf16_t* VT    = (bf16_t*)alloc((size_t)NKV * HD * SEQ * 2);
  bf16_t* Oa    = (bf16_t*)alloc((size_t)SEQ * QSZ * 2);
  (void)ws_size; (void)in_sizes; (void)n_in; (void)out_size;

  cast_f32_bf16<<<SEQ * HIDDEN / 4 / 256, 256, 0, stream>>>(hidden, h_bf);
  transpose_cast<<<dim3(QKVN / 32, HIDDEN / 32), 256, 0, stream>>>(w_qkv, wqkvT, HIDDEN, QKVN);
  transpose_cast<<<dim3(HIDDEN / 32, QSZ / 32), 256, 0, stream>>>(w_o, woT, QSZ, HIDDEN);
  gemm_bf16_bt<<<dim3(QKVN / 128, SEQ / 128), 256, 0, stream>>>(h_bf, wqkvT, qkv, SEQ, QKVN, HIDDEN);
  rope_qk<<<SEQ, 256, 0, stream>>>(qkv, positions, Qh, Kh);
  vprep<<<dim3(SEQ / 32, HD / 32, NKV), 256, 0, stream>>>(qkv, VT);
  attn_kernel<<<dim3(16, NH), 256, 0, stream>>>(Qh, Kh, VT, Oa);
  gemm_bf16_bt<<<dim3(HIDDEN / 128, SEQ / 128), 256, 0, stream>>>(Oa, woT, out, SEQ, HIDDEN, QSZ);
}